// Round 1
// baseline (90.892 us; speedup 1.0000x reference)
//
#include <hip/hip_runtime.h>
#include <hip/hip_bf16.h>
#include <math.h>

#define BB 4
#define CC 256
#define HH 100
#define WW 100
#define HWP (HH * WW)

// ---------------------------------------------------------------------------
// Pass 1: transpose+convert  x[b,c,h,w] f32  ->  xT[((b*H+h)*W+w)*C + c] bf16
// One block per (b,h) row-plane; LDS-staged so both global read and write
// are coalesced.
// ---------------------------------------------------------------------------
__global__ __launch_bounds__(256) void transpose_kernel(
    const float* __restrict__ x, ushort* __restrict__ xT) {
    __shared__ ushort tile[CC][WW + 1];   // 256*101*2 = 51.7 KB
    int bh = blockIdx.x;                  // 0..B*H-1
    int b = bh / HH;
    const float* src = x + (size_t)b * CC * HWP + (size_t)(bh - b * HH) * WW;
    for (int idx = threadIdx.x; idx < CC * WW; idx += 256) {
        int c = idx / WW;
        int w = idx - c * WW;
        float v = src[(size_t)c * HWP + w];
        __hip_bfloat16 bv = __float2bfloat16(v);
        tile[c][w] = *reinterpret_cast<ushort*>(&bv);
    }
    __syncthreads();
    ushort* dst = xT + (size_t)bh * WW * CC;   // dst[w*C + c]
    for (int idx = threadIdx.x; idx < WW * CC; idx += 256) {
        int w = idx / CC;
        int c = idx - w * CC;
        dst[idx] = tile[c][w];
    }
}

// ---------------------------------------------------------------------------
// Pass 2: one block (128 threads) per output pixel. Thread t handles channels
// 2t and 2t+1 (packed bf16x2 loads from transposed layout). 9 taps, bilinear
// with validity folded into weights, per-channel max, then w0-dot reduce.
// ---------------------------------------------------------------------------
template <bool TRANSPOSED>
__global__ __launch_bounds__(128) void deform_kernel(
    const ushort* __restrict__ xT, const float* __restrict__ x,
    const float* __restrict__ off, const float* __restrict__ w0,
    const float* __restrict__ b0, float* __restrict__ out) {
    int p = blockIdx.x;                 // 0..B*H*W-1
    int b = p / HWP;
    int hw = p - b * HWP;
    int h = hw / WW;
    int w = hw - h * WW;
    int tid = threadIdx.x;              // channel pair index

    const float* offp = off + (size_t)b * 18 * HWP + hw;
    const uint* xTu = reinterpret_cast<const uint*>(xT);  // 2 bf16 per uint
    int bH = b * HH;
    // untransposed fallback base: x[b, 2*tid, :, :]
    const float* xb = x + (size_t)b * CC * HWP + (size_t)(2 * tid) * HWP;

    float m0 = -INFINITY, m1 = -INFINITY;

#pragma unroll
    for (int k = 0; k < 9; ++k) {
        int kh = k / 3 - 1;
        int kw = k - (k / 3) * 3 - 1;
        float dy = offp[(size_t)(2 * k) * HWP];
        float dx = offp[(size_t)(2 * k + 1) * HWP];
        float py = (float)(h + kh) + dy;
        float px = (float)(w + kw) + dx;
        float y0f = floorf(py), x0f = floorf(px);
        float wy = py - y0f, wx = px - x0f;
        int y0 = (int)y0f, x0 = (int)x0f;
        int y1 = y0 + 1, x1 = x0 + 1;
        bool vy0 = (y0 >= 0) && (y0 < HH);
        bool vy1 = (y1 >= 0) && (y1 < HH);
        bool vx0 = (x0 >= 0) && (x0 < WW);
        bool vx1 = (x1 >= 0) && (x1 < WW);
        int yc0 = min(max(y0, 0), HH - 1);
        int yc1 = min(max(y1, 0), HH - 1);
        int xc0 = min(max(x0, 0), WW - 1);
        int xc1 = min(max(x1, 0), WW - 1);
        float w00 = (1.f - wy) * (1.f - wx) * (float)(vy0 && vx0);
        float w01 = (1.f - wy) * wx * (float)(vy0 && vx1);
        float w10 = wy * (1.f - wx) * (float)(vy1 && vx0);
        float w11 = wy * wx * (float)(vy1 && vx1);

        float f00l, f00h, f01l, f01h, f10l, f10h, f11l, f11h;
        if (TRANSPOSED) {
            uint u00 = xTu[(size_t)((bH + yc0) * WW + xc0) * 128 + tid];
            uint u01 = xTu[(size_t)((bH + yc0) * WW + xc1) * 128 + tid];
            uint u10 = xTu[(size_t)((bH + yc1) * WW + xc0) * 128 + tid];
            uint u11 = xTu[(size_t)((bH + yc1) * WW + xc1) * 128 + tid];
            f00l = __uint_as_float(u00 << 16);
            f00h = __uint_as_float(u00 & 0xffff0000u);
            f01l = __uint_as_float(u01 << 16);
            f01h = __uint_as_float(u01 & 0xffff0000u);
            f10l = __uint_as_float(u10 << 16);
            f10h = __uint_as_float(u10 & 0xffff0000u);
            f11l = __uint_as_float(u11 << 16);
            f11h = __uint_as_float(u11 & 0xffff0000u);
        } else {
            int o00 = yc0 * WW + xc0, o01 = yc0 * WW + xc1;
            int o10 = yc1 * WW + xc0, o11 = yc1 * WW + xc1;
            f00l = xb[o00];            f00h = xb[o00 + HWP];
            f01l = xb[o01];            f01h = xb[o01 + HWP];
            f10l = xb[o10];            f10h = xb[o10 + HWP];
            f11l = xb[o11];            f11h = xb[o11 + HWP];
        }
        float s0 = f00l * w00 + f01l * w01 + f10l * w10 + f11l * w11;
        float s1 = f00h * w00 + f01h * w01 + f10h * w10 + f11h * w11;
        m0 = fmaxf(m0, s0);
        m1 = fmaxf(m1, s1);
    }

    float2 wv = reinterpret_cast<const float2*>(w0)[tid];
    float partial = m0 * wv.x + m1 * wv.y;
#pragma unroll
    for (int d = 32; d > 0; d >>= 1) partial += __shfl_down(partial, d, 64);

    __shared__ float red[2];
    if ((tid & 63) == 0) red[tid >> 6] = partial;
    __syncthreads();
    if (tid == 0) {
        float z = red[0] + red[1] + b0[0];
        out[p] = 1.f / (1.f + expf(-z));
    }
}

extern "C" void kernel_launch(void* const* d_in, const int* in_sizes, int n_in,
                              void* d_out, int out_size, void* d_ws, size_t ws_size,
                              hipStream_t stream) {
    const float* x   = (const float*)d_in[0];
    const float* off = (const float*)d_in[1];
    const float* w0  = (const float*)d_in[2];
    const float* b0  = (const float*)d_in[3];
    float* out = (float*)d_out;

    const size_t xT_bytes = (size_t)BB * HH * WW * CC * sizeof(ushort);  // 20.48 MB
    if (ws_size >= xT_bytes) {
        ushort* xT = (ushort*)d_ws;
        transpose_kernel<<<BB * HH, 256, 0, stream>>>(x, xT);
        deform_kernel<true><<<BB * HWP, 128, 0, stream>>>(xT, x, off, w0, b0, out);
    } else {
        deform_kernel<false><<<BB * HWP, 128, 0, stream>>>(nullptr, x, off, w0, b0, out);
    }
}

// Round 2
// 75.325 us; speedup vs baseline: 1.2067x; 1.2067x over previous
//
#include <hip/hip_runtime.h>
#include <hip/hip_bf16.h>
#include <math.h>

#define BB 4
#define CC 256
#define HH 100
#define WW 100
#define HWP (HH * WW)
#define NPIX (BB * HWP)

#define XT_BYTES ((size_t)NPIX * CC * 2)          // 20,480,000
#define GEOM_BYTES ((size_t)NPIX * 9 * 32)        // 11,520,000

// ---------------------------------------------------------------------------
// Pass 1: transpose+convert  x[b,c,h,w] f32  ->  xT[((b*H+h)*W+w)*C + c] bf16
// ---------------------------------------------------------------------------
__global__ __launch_bounds__(256) void transpose_kernel(
    const float* __restrict__ x, ushort* __restrict__ xT) {
    __shared__ ushort tile[CC][WW + 1];   // 51.7 KB
    int bh = blockIdx.x;                  // 0..B*H-1
    int b = bh / HH;
    const float* src = x + (size_t)b * CC * HWP + (size_t)(bh - b * HH) * WW;
    for (int idx = threadIdx.x; idx < CC * WW; idx += 256) {
        int c = idx / WW;
        int w = idx - c * WW;
        float v = src[(size_t)c * HWP + w];
        __hip_bfloat16 bv = __float2bfloat16(v);
        tile[c][w] = *reinterpret_cast<ushort*>(&bv);
    }
    __syncthreads();
    ushort* dst = xT + (size_t)bh * WW * CC;   // dst[w*C + c]
    for (int idx = threadIdx.x; idx < WW * CC; idx += 256) {
        int w = idx / CC;
        int c = idx - w * CC;
        dst[idx] = tile[c][w];
    }
}

// ---------------------------------------------------------------------------
// Pass 1b: per-(pixel,tap) geometry: 4 corner byte-offsets into xT + 4 weights.
// Record: int4{o00,o01,o10,o11}, float4{w00,w01,w10,w11}  (32 B)
// ---------------------------------------------------------------------------
__global__ __launch_bounds__(256) void geom_kernel(
    const float* __restrict__ off, int4* __restrict__ geom) {
    int p = blockIdx.x * 256 + threadIdx.x;
    if (p >= NPIX) return;
    int b = p / HWP;
    int hw = p - b * HWP;
    int h = hw / WW;
    int w = hw - h * WW;
    const float* offp = off + (size_t)b * 18 * HWP + hw;
    int bH = b * HH;
#pragma unroll
    for (int k = 0; k < 9; ++k) {
        int kh = k / 3 - 1;
        int kw = k - (k / 3) * 3 - 1;
        float dy = offp[(size_t)(2 * k) * HWP];
        float dx = offp[(size_t)(2 * k + 1) * HWP];
        float py = (float)(h + kh) + dy;
        float px = (float)(w + kw) + dx;
        float y0f = floorf(py), x0f = floorf(px);
        float wy = py - y0f, wx = px - x0f;
        int y0 = (int)y0f, x0 = (int)x0f;
        int y1 = y0 + 1, x1 = x0 + 1;
        bool vy0 = (y0 >= 0) && (y0 < HH);
        bool vy1 = (y1 >= 0) && (y1 < HH);
        bool vx0 = (x0 >= 0) && (x0 < WW);
        bool vx1 = (x1 >= 0) && (x1 < WW);
        int yc0 = min(max(y0, 0), HH - 1);
        int yc1 = min(max(y1, 0), HH - 1);
        int xc0 = min(max(x0, 0), WW - 1);
        int xc1 = min(max(x1, 0), WW - 1);
        float w00 = (1.f - wy) * (1.f - wx) * (float)(vy0 && vx0);
        float w01 = (1.f - wy) * wx * (float)(vy0 && vx1);
        float w10 = wy * (1.f - wx) * (float)(vy1 && vx0);
        float w11 = wy * wx * (float)(vy1 && vx1);
        int o00 = ((bH + yc0) * WW + xc0) * (CC * 2);
        int o01 = ((bH + yc0) * WW + xc1) * (CC * 2);
        int o10 = ((bH + yc1) * WW + xc0) * (CC * 2);
        int o11 = ((bH + yc1) * WW + xc1) * (CC * 2);
        int4* rec = geom + ((size_t)p * 9 + k) * 2;
        rec[0] = make_int4(o00, o01, o10, o11);
        reinterpret_cast<float4*>(rec)[1] = make_float4(w00, w01, w10, w11);
    }
}

// ---------------------------------------------------------------------------
// Pass 2: 256 threads = 4 waves per block; each WAVE owns one pixel.
// Lane handles 4 channels (one uint2 = 4 bf16). Geometry comes from the
// precomputed table via a wave-uniform (readfirstlane) pointer -> s_load,
// weights live in SGPRs. XCD-chunked block swizzle for L2 locality.
// ---------------------------------------------------------------------------
__global__ __launch_bounds__(256) void deform2_kernel(
    const char* __restrict__ xTb, const int4* __restrict__ geom,
    const float* __restrict__ w0, const float* __restrict__ b0,
    float* __restrict__ out, int nblk) {
    // bijective XCD chunk swizzle
    int orig = blockIdx.x;
    int q = nblk / 8, r = nblk % 8;
    int xcd = orig % 8, idx = orig / 8;
    int bid = (xcd < r) ? (xcd * (q + 1) + idx)
                        : (r * (q + 1) + (xcd - r) * q + idx);

    int lane = threadIdx.x & 63;
    int wid = threadIdx.x >> 6;
    int p = __builtin_amdgcn_readfirstlane(bid * 4 + wid);  // wave-uniform pixel

    const int4* g = geom + (size_t)p * 9 * 2;
    int laneOff = lane * 8;

    float m0 = -INFINITY, m1 = -INFINITY, m2 = -INFINITY, m3 = -INFINITY;

#pragma unroll
    for (int k = 0; k < 9; ++k) {
        int4 o = g[k * 2];
        float4 wv = reinterpret_cast<const float4*>(g)[k * 2 + 1];
        uint2 u00 = *reinterpret_cast<const uint2*>(xTb + o.x + laneOff);
        uint2 u01 = *reinterpret_cast<const uint2*>(xTb + o.y + laneOff);
        uint2 u10 = *reinterpret_cast<const uint2*>(xTb + o.z + laneOff);
        uint2 u11 = *reinterpret_cast<const uint2*>(xTb + o.w + laneOff);

        float s0 = __uint_as_float(u00.x << 16) * wv.x;
        float s1 = __uint_as_float(u00.x & 0xffff0000u) * wv.x;
        float s2 = __uint_as_float(u00.y << 16) * wv.x;
        float s3 = __uint_as_float(u00.y & 0xffff0000u) * wv.x;
        s0 = fmaf(__uint_as_float(u01.x << 16), wv.y, s0);
        s1 = fmaf(__uint_as_float(u01.x & 0xffff0000u), wv.y, s1);
        s2 = fmaf(__uint_as_float(u01.y << 16), wv.y, s2);
        s3 = fmaf(__uint_as_float(u01.y & 0xffff0000u), wv.y, s3);
        s0 = fmaf(__uint_as_float(u10.x << 16), wv.z, s0);
        s1 = fmaf(__uint_as_float(u10.x & 0xffff0000u), wv.z, s1);
        s2 = fmaf(__uint_as_float(u10.y << 16), wv.z, s2);
        s3 = fmaf(__uint_as_float(u10.y & 0xffff0000u), wv.z, s3);
        s0 = fmaf(__uint_as_float(u11.x << 16), wv.w, s0);
        s1 = fmaf(__uint_as_float(u11.x & 0xffff0000u), wv.w, s1);
        s2 = fmaf(__uint_as_float(u11.y << 16), wv.w, s2);
        s3 = fmaf(__uint_as_float(u11.y & 0xffff0000u), wv.w, s3);
        m0 = fmaxf(m0, s0);
        m1 = fmaxf(m1, s1);
        m2 = fmaxf(m2, s2);
        m3 = fmaxf(m3, s3);
    }

    float4 wq = reinterpret_cast<const float4*>(w0)[lane];  // channels 4l..4l+3
    float part = m0 * wq.x + m1 * wq.y + m2 * wq.z + m3 * wq.w;
#pragma unroll
    for (int d = 32; d > 0; d >>= 1) part += __shfl_down(part, d, 64);
    if (lane == 0) {
        float z = part + b0[0];
        out[p] = 1.f / (1.f + expf(-z));
    }
}

// ---------------------------------------------------------------------------
// Fallback (R0 kernel): one block (128 threads) per pixel, inline geometry.
// ---------------------------------------------------------------------------
template <bool TRANSPOSED>
__global__ __launch_bounds__(128) void deform_kernel(
    const ushort* __restrict__ xT, const float* __restrict__ x,
    const float* __restrict__ off, const float* __restrict__ w0,
    const float* __restrict__ b0, float* __restrict__ out) {
    int p = blockIdx.x;
    int b = p / HWP;
    int hw = p - b * HWP;
    int h = hw / WW;
    int w = hw - h * WW;
    int tid = threadIdx.x;

    const float* offp = off + (size_t)b * 18 * HWP + hw;
    const uint* xTu = reinterpret_cast<const uint*>(xT);
    int bH = b * HH;
    const float* xb = x + (size_t)b * CC * HWP + (size_t)(2 * tid) * HWP;

    float m0 = -INFINITY, m1 = -INFINITY;

#pragma unroll
    for (int k = 0; k < 9; ++k) {
        int kh = k / 3 - 1;
        int kw = k - (k / 3) * 3 - 1;
        float dy = offp[(size_t)(2 * k) * HWP];
        float dx = offp[(size_t)(2 * k + 1) * HWP];
        float py = (float)(h + kh) + dy;
        float px = (float)(w + kw) + dx;
        float y0f = floorf(py), x0f = floorf(px);
        float wy = py - y0f, wx = px - x0f;
        int y0 = (int)y0f, x0 = (int)x0f;
        int y1 = y0 + 1, x1 = x0 + 1;
        bool vy0 = (y0 >= 0) && (y0 < HH);
        bool vy1 = (y1 >= 0) && (y1 < HH);
        bool vx0 = (x0 >= 0) && (x0 < WW);
        bool vx1 = (x1 >= 0) && (x1 < WW);
        int yc0 = min(max(y0, 0), HH - 1);
        int yc1 = min(max(y1, 0), HH - 1);
        int xc0 = min(max(x0, 0), WW - 1);
        int xc1 = min(max(x1, 0), WW - 1);
        float w00 = (1.f - wy) * (1.f - wx) * (float)(vy0 && vx0);
        float w01 = (1.f - wy) * wx * (float)(vy0 && vx1);
        float w10 = wy * (1.f - wx) * (float)(vy1 && vx0);
        float w11 = wy * wx * (float)(vy1 && vx1);

        float f00l, f00h, f01l, f01h, f10l, f10h, f11l, f11h;
        if (TRANSPOSED) {
            uint u00 = xTu[(size_t)((bH + yc0) * WW + xc0) * 128 + tid];
            uint u01 = xTu[(size_t)((bH + yc0) * WW + xc1) * 128 + tid];
            uint u10 = xTu[(size_t)((bH + yc1) * WW + xc0) * 128 + tid];
            uint u11 = xTu[(size_t)((bH + yc1) * WW + xc1) * 128 + tid];
            f00l = __uint_as_float(u00 << 16);
            f00h = __uint_as_float(u00 & 0xffff0000u);
            f01l = __uint_as_float(u01 << 16);
            f01h = __uint_as_float(u01 & 0xffff0000u);
            f10l = __uint_as_float(u10 << 16);
            f10h = __uint_as_float(u10 & 0xffff0000u);
            f11l = __uint_as_float(u11 << 16);
            f11h = __uint_as_float(u11 & 0xffff0000u);
        } else {
            int o00 = yc0 * WW + xc0, o01 = yc0 * WW + xc1;
            int o10 = yc1 * WW + xc0, o11 = yc1 * WW + xc1;
            f00l = xb[o00];            f00h = xb[o00 + HWP];
            f01l = xb[o01];            f01h = xb[o01 + HWP];
            f10l = xb[o10];            f10h = xb[o10 + HWP];
            f11l = xb[o11];            f11h = xb[o11 + HWP];
        }
        float s0 = f00l * w00 + f01l * w01 + f10l * w10 + f11l * w11;
        float s1 = f00h * w00 + f01h * w01 + f10h * w10 + f11h * w11;
        m0 = fmaxf(m0, s0);
        m1 = fmaxf(m1, s1);
    }

    float2 wv = reinterpret_cast<const float2*>(w0)[tid];
    float partial = m0 * wv.x + m1 * wv.y;
#pragma unroll
    for (int d = 32; d > 0; d >>= 1) partial += __shfl_down(partial, d, 64);

    __shared__ float red[2];
    if ((tid & 63) == 0) red[tid >> 6] = partial;
    __syncthreads();
    if (tid == 0) {
        float z = red[0] + red[1] + b0[0];
        out[p] = 1.f / (1.f + expf(-z));
    }
}

extern "C" void kernel_launch(void* const* d_in, const int* in_sizes, int n_in,
                              void* d_out, int out_size, void* d_ws, size_t ws_size,
                              hipStream_t stream) {
    const float* x   = (const float*)d_in[0];
    const float* off = (const float*)d_in[1];
    const float* w0  = (const float*)d_in[2];
    const float* b0  = (const float*)d_in[3];
    float* out = (float*)d_out;

    if (ws_size >= XT_BYTES + GEOM_BYTES) {
        ushort* xT = (ushort*)d_ws;
        int4* geom = (int4*)((char*)d_ws + XT_BYTES);
        transpose_kernel<<<BB * HH, 256, 0, stream>>>(x, xT);
        geom_kernel<<<(NPIX + 255) / 256, 256, 0, stream>>>(off, geom);
        int nblk = NPIX / 4;  // 10000
        deform2_kernel<<<nblk, 256, 0, stream>>>((const char*)d_ws, geom, w0, b0, out, nblk);
    } else if (ws_size >= XT_BYTES) {
        ushort* xT = (ushort*)d_ws;
        transpose_kernel<<<BB * HH, 256, 0, stream>>>(x, xT);
        deform_kernel<true><<<NPIX, 128, 0, stream>>>(xT, x, off, w0, b0, out);
    } else {
        deform_kernel<false><<<NPIX, 128, 0, stream>>>(nullptr, x, off, w0, b0, out);
    }
}

// Round 4
// 67.372 us; speedup vs baseline: 1.3491x; 1.1181x over previous
//
#include <hip/hip_runtime.h>
#include <hip/hip_fp16.h>
#include <math.h>

#define BB 4
#define CC 256
#define HH 100
#define WW 100
#define HWP (HH * WW)
#define NPIX (BB * HWP)

#define XT_BYTES ((size_t)NPIX * CC * 2)          // 20,480,000
#define GEOM_BYTES ((size_t)NPIX * 9 * 32)        // 11,520,000

// ROCm 7.2 hip_fp16.h lacks __hmax2 — emit v_pk_max_f16 directly.
static __device__ inline uint pk_max_f16(uint a, uint b) {
    uint r;
    asm("v_pk_max_f16 %0, %1, %2" : "=v"(r) : "v"(a), "v"(b));
    return r;
}

// ---------------------------------------------------------------------------
// Pass 1: transpose+convert  x[b,c,h,w] f32 -> xT[((b*H+h)*W+w)*C + c] fp16.
// One block per (b,h). float4 reads, packed uint (2ch) LDS tile, uint2 writes.
// ---------------------------------------------------------------------------
__global__ __launch_bounds__(256) void transpose_kernel(
    const float* __restrict__ x, ushort* __restrict__ xT) {
    __shared__ uint tileT[WW][CC / 2 + 1];   // 100 x 129 x 4B = 51.6 KB
    int bh = blockIdx.x;                     // 0..B*H-1
    int b = bh / HH;
    int h = bh - b * HH;
    const float* src = x + (size_t)b * CC * HWP + (size_t)h * WW;

    // read: idx over (CC/2)*25; c2 = channel pair, w4 = float4 column group
    for (int idx = threadIdx.x; idx < (CC / 2) * 25; idx += 256) {
        int c2 = idx / 25;
        int w4 = idx - c2 * 25;
        const float* p0 = src + (size_t)(2 * c2) * HWP + w4 * 4;
        float4 va = *reinterpret_cast<const float4*>(p0);        // channel 2*c2
        float4 vb = *reinterpret_cast<const float4*>(p0 + HWP);  // channel 2*c2+1
        __half2 h0 = __floats2half2_rn(va.x, vb.x);
        __half2 h1 = __floats2half2_rn(va.y, vb.y);
        __half2 h2 = __floats2half2_rn(va.z, vb.z);
        __half2 h3 = __floats2half2_rn(va.w, vb.w);
        tileT[w4 * 4 + 0][c2] = *reinterpret_cast<uint*>(&h0);
        tileT[w4 * 4 + 1][c2] = *reinterpret_cast<uint*>(&h1);
        tileT[w4 * 4 + 2][c2] = *reinterpret_cast<uint*>(&h2);
        tileT[w4 * 4 + 3][c2] = *reinterpret_cast<uint*>(&h3);
    }
    __syncthreads();

    // write: uint2 (4 channels), coalesced 512B/wave
    uint2* dst = reinterpret_cast<uint2*>(xT + (size_t)bh * WW * CC);
    for (int idx = threadIdx.x; idx < WW * (CC / 4); idx += 256) {
        int w = idx >> 6;           // CC/4 = 64
        int c4 = idx & 63;
        dst[idx] = make_uint2(tileT[w][2 * c4], tileT[w][2 * c4 + 1]);
    }
}

// ---------------------------------------------------------------------------
// Pass 1b: per-(pixel,tap) geometry: 4 corner byte-offsets into xT +
// 4 weights pre-packed as broadcast half2. Record = int4 + uint4 (32 B).
// ---------------------------------------------------------------------------
__global__ __launch_bounds__(256) void geom_kernel(
    const float* __restrict__ off, int4* __restrict__ geom) {
    int p = blockIdx.x * 256 + threadIdx.x;
    if (p >= NPIX) return;
    int b = p / HWP;
    int hw = p - b * HWP;
    int h = hw / WW;
    int w = hw - h * WW;
    const float* offp = off + (size_t)b * 18 * HWP + hw;
    int bH = b * HH;
#pragma unroll
    for (int k = 0; k < 9; ++k) {
        int kh = k / 3 - 1;
        int kw = k - (k / 3) * 3 - 1;
        float dy = offp[(size_t)(2 * k) * HWP];
        float dx = offp[(size_t)(2 * k + 1) * HWP];
        float py = (float)(h + kh) + dy;
        float px = (float)(w + kw) + dx;
        float y0f = floorf(py), x0f = floorf(px);
        float wy = py - y0f, wx = px - x0f;
        int y0 = (int)y0f, x0 = (int)x0f;
        int y1 = y0 + 1, x1 = x0 + 1;
        bool vy0 = (y0 >= 0) && (y0 < HH);
        bool vy1 = (y1 >= 0) && (y1 < HH);
        bool vx0 = (x0 >= 0) && (x0 < WW);
        bool vx1 = (x1 >= 0) && (x1 < WW);
        int yc0 = min(max(y0, 0), HH - 1);
        int yc1 = min(max(y1, 0), HH - 1);
        int xc0 = min(max(x0, 0), WW - 1);
        int xc1 = min(max(x1, 0), WW - 1);
        float w00 = (1.f - wy) * (1.f - wx) * (float)(vy0 && vx0);
        float w01 = (1.f - wy) * wx * (float)(vy0 && vx1);
        float w10 = wy * (1.f - wx) * (float)(vy1 && vx0);
        float w11 = wy * wx * (float)(vy1 && vx1);
        int o00 = ((bH + yc0) * WW + xc0) * (CC * 2);
        int o01 = ((bH + yc0) * WW + xc1) * (CC * 2);
        int o10 = ((bH + yc1) * WW + xc0) * (CC * 2);
        int o11 = ((bH + yc1) * WW + xc1) * (CC * 2);
        __half2 h00 = __floats2half2_rn(w00, w00);
        __half2 h01 = __floats2half2_rn(w01, w01);
        __half2 h10 = __floats2half2_rn(w10, w10);
        __half2 h11 = __floats2half2_rn(w11, w11);
        int4* rec = geom + ((size_t)p * 9 + k) * 2;
        rec[0] = make_int4(o00, o01, o10, o11);
        rec[1] = make_int4(*reinterpret_cast<int*>(&h00), *reinterpret_cast<int*>(&h01),
                           *reinterpret_cast<int*>(&h10), *reinterpret_cast<int*>(&h11));
    }
}

// ---------------------------------------------------------------------------
// Pass 2: 256 threads = 4 waves per block; each WAVE owns one pixel.
// Lane = 4 channels (uint2 = 2x half2). Packed fp16 FMA/max; geometry via
// wave-uniform s_load with weights broadcast from SGPRs.
// ---------------------------------------------------------------------------
__global__ __launch_bounds__(256) void deform2_kernel(
    const char* __restrict__ xTb, const int4* __restrict__ geom,
    const float* __restrict__ w0, const float* __restrict__ b0,
    float* __restrict__ out, int nblk) {
    // bijective XCD chunk swizzle
    int orig = blockIdx.x;
    int q = nblk / 8, r = nblk % 8;
    int xcd = orig % 8, idx = orig / 8;
    int bid = (xcd < r) ? (xcd * (q + 1) + idx)
                        : (r * (q + 1) + (xcd - r) * q + idx);

    int lane = threadIdx.x & 63;
    int wid = threadIdx.x >> 6;
    int p = __builtin_amdgcn_readfirstlane(bid * 4 + wid);  // wave-uniform pixel

    const int4* g = geom + (size_t)p * 9 * 2;
    int laneOff = lane * 8;

    const ushort NEG_INF_H = 0xFC00;
    uint m0 = ((uint)NEG_INF_H << 16) | NEG_INF_H;
    uint m1 = m0;

#pragma unroll
    for (int k = 0; k < 9; ++k) {
        int4 o = g[k * 2];
        int4 wb = g[k * 2 + 1];
        __half2 w00 = *reinterpret_cast<__half2*>(&wb.x);
        __half2 w01 = *reinterpret_cast<__half2*>(&wb.y);
        __half2 w10 = *reinterpret_cast<__half2*>(&wb.z);
        __half2 w11 = *reinterpret_cast<__half2*>(&wb.w);
        uint2 u00 = *reinterpret_cast<const uint2*>(xTb + o.x + laneOff);
        uint2 u01 = *reinterpret_cast<const uint2*>(xTb + o.y + laneOff);
        uint2 u10 = *reinterpret_cast<const uint2*>(xTb + o.z + laneOff);
        uint2 u11 = *reinterpret_cast<const uint2*>(xTb + o.w + laneOff);

        __half2 a; uint au;
        au = u00.x; a = *reinterpret_cast<__half2*>(&au);
        __half2 acc0 = __hmul2(a, w00);
        au = u00.y; a = *reinterpret_cast<__half2*>(&au);
        __half2 acc1 = __hmul2(a, w00);
        au = u01.x; a = *reinterpret_cast<__half2*>(&au);
        acc0 = __hfma2(a, w01, acc0);
        au = u01.y; a = *reinterpret_cast<__half2*>(&au);
        acc1 = __hfma2(a, w01, acc1);
        au = u10.x; a = *reinterpret_cast<__half2*>(&au);
        acc0 = __hfma2(a, w10, acc0);
        au = u10.y; a = *reinterpret_cast<__half2*>(&au);
        acc1 = __hfma2(a, w10, acc1);
        au = u11.x; a = *reinterpret_cast<__half2*>(&au);
        acc0 = __hfma2(a, w11, acc0);
        au = u11.y; a = *reinterpret_cast<__half2*>(&au);
        acc1 = __hfma2(a, w11, acc1);

        m0 = pk_max_f16(m0, *reinterpret_cast<uint*>(&acc0));
        m1 = pk_max_f16(m1, *reinterpret_cast<uint*>(&acc1));
    }

    float2 f0 = __half22float2(*reinterpret_cast<__half2*>(&m0)); // ch 4l,4l+1
    float2 f1 = __half22float2(*reinterpret_cast<__half2*>(&m1)); // ch 4l+2,4l+3
    float4 wq = reinterpret_cast<const float4*>(w0)[lane];
    float part = f0.x * wq.x + f0.y * wq.y + f1.x * wq.z + f1.y * wq.w;
#pragma unroll
    for (int d = 32; d > 0; d >>= 1) part += __shfl_down(part, d, 64);
    if (lane == 0) {
        float z = part + b0[0];
        out[p] = 1.f / (1.f + expf(-z));
    }
}

// ---------------------------------------------------------------------------
// Fallback: one block (128 threads) per pixel, f32 path, no workspace needed.
// ---------------------------------------------------------------------------
__global__ __launch_bounds__(128) void deform_fallback_kernel(
    const float* __restrict__ x, const float* __restrict__ off,
    const float* __restrict__ w0, const float* __restrict__ b0,
    float* __restrict__ out) {
    int p = blockIdx.x;
    int b = p / HWP;
    int hw = p - b * HWP;
    int h = hw / WW;
    int w = hw - h * WW;
    int tid = threadIdx.x;

    const float* offp = off + (size_t)b * 18 * HWP + hw;
    const float* xb = x + (size_t)b * CC * HWP + (size_t)(2 * tid) * HWP;

    float m0 = -INFINITY, m1 = -INFINITY;

#pragma unroll
    for (int k = 0; k < 9; ++k) {
        int kh = k / 3 - 1;
        int kw = k - (k / 3) * 3 - 1;
        float dy = offp[(size_t)(2 * k) * HWP];
        float dx = offp[(size_t)(2 * k + 1) * HWP];
        float py = (float)(h + kh) + dy;
        float px = (float)(w + kw) + dx;
        float y0f = floorf(py), x0f = floorf(px);
        float wy = py - y0f, wx = px - x0f;
        int y0 = (int)y0f, x0 = (int)x0f;
        int y1 = y0 + 1, x1 = x0 + 1;
        bool vy0 = (y0 >= 0) && (y0 < HH);
        bool vy1 = (y1 >= 0) && (y1 < HH);
        bool vx0 = (x0 >= 0) && (x0 < WW);
        bool vx1 = (x1 >= 0) && (x1 < WW);
        int yc0 = min(max(y0, 0), HH - 1);
        int yc1 = min(max(y1, 0), HH - 1);
        int xc0 = min(max(x0, 0), WW - 1);
        int xc1 = min(max(x1, 0), WW - 1);
        float w00 = (1.f - wy) * (1.f - wx) * (float)(vy0 && vx0);
        float w01 = (1.f - wy) * wx * (float)(vy0 && vx1);
        float w10 = wy * (1.f - wx) * (float)(vy1 && vx0);
        float w11 = wy * wx * (float)(vy1 && vx1);

        int o00 = yc0 * WW + xc0, o01 = yc0 * WW + xc1;
        int o10 = yc1 * WW + xc0, o11 = yc1 * WW + xc1;
        float s0 = xb[o00] * w00 + xb[o01] * w01 + xb[o10] * w10 + xb[o11] * w11;
        float s1 = xb[o00 + HWP] * w00 + xb[o01 + HWP] * w01 +
                   xb[o10 + HWP] * w10 + xb[o11 + HWP] * w11;
        m0 = fmaxf(m0, s0);
        m1 = fmaxf(m1, s1);
    }

    float2 wv = reinterpret_cast<const float2*>(w0)[tid];
    float partial = m0 * wv.x + m1 * wv.y;
#pragma unroll
    for (int d = 32; d > 0; d >>= 1) partial += __shfl_down(partial, d, 64);

    __shared__ float red[2];
    if ((tid & 63) == 0) red[tid >> 6] = partial;
    __syncthreads();
    if (tid == 0) {
        float z = red[0] + red[1] + b0[0];
        out[p] = 1.f / (1.f + expf(-z));
    }
}

extern "C" void kernel_launch(void* const* d_in, const int* in_sizes, int n_in,
                              void* d_out, int out_size, void* d_ws, size_t ws_size,
                              hipStream_t stream) {
    const float* x   = (const float*)d_in[0];
    const float* off = (const float*)d_in[1];
    const float* w0  = (const float*)d_in[2];
    const float* b0  = (const float*)d_in[3];
    float* out = (float*)d_out;

    if (ws_size >= XT_BYTES + GEOM_BYTES) {
        ushort* xT = (ushort*)d_ws;
        int4* geom = (int4*)((char*)d_ws + XT_BYTES);
        transpose_kernel<<<BB * HH, 256, 0, stream>>>(x, xT);
        geom_kernel<<<(NPIX + 255) / 256, 256, 0, stream>>>(off, geom);
        int nblk = NPIX / 4;  // 10000
        deform2_kernel<<<nblk, 256, 0, stream>>>((const char*)d_ws, geom, w0, b0, out, nblk);
    } else {
        deform_fallback_kernel<<<NPIX, 128, 0, stream>>>(x, off, w0, b0, out);
    }
}

// Round 5
// 64.498 us; speedup vs baseline: 1.4092x; 1.0446x over previous
//
#include <hip/hip_runtime.h>
#include <hip/hip_fp16.h>
#include <math.h>

#define BB 4
#define CC 256
#define HH 100
#define WW 100
#define HWP (HH * WW)
#define NPIX (BB * HWP)

#define XT_BYTES ((size_t)NPIX * CC * 2)          // 20,480,000
#define GEOM_BYTES ((size_t)NPIX * 9 * 32)        // 11,520,000

#define NT_BLOCKS (BB * HH)                       // 400 transpose blocks
#define NG_BLOCKS ((NPIX + 255) / 256)            // 157 geom blocks

// ROCm 7.2 hip_fp16.h lacks __hmax2 — emit v_pk_max_f16 directly.
static __device__ inline uint pk_max_f16(uint a, uint b) {
    uint r;
    asm("v_pk_max_f16 %0, %1, %2" : "=v"(r) : "v"(a), "v"(b));
    return r;
}

// ---------------------------------------------------------------------------
// Prep kernel: blocks [0,400) transpose+convert x -> xT fp16 channel-last;
// blocks [400, 400+157) compute per-(pixel,tap) geometry records.
// ---------------------------------------------------------------------------
__global__ __launch_bounds__(256) void prep_kernel(
    const float* __restrict__ x, ushort* __restrict__ xT,
    const float* __restrict__ off, int4* __restrict__ geom) {
    __shared__ uint tileT[WW][CC / 2 + 1];   // 100 x 129 x 4B = 51.6 KB

    if (blockIdx.x < NT_BLOCKS) {
        int bh = blockIdx.x;                 // 0..B*H-1
        int b = bh / HH;
        int h = bh - b * HH;
        const float* src = x + (size_t)b * CC * HWP + (size_t)h * WW;

        for (int idx = threadIdx.x; idx < (CC / 2) * 25; idx += 256) {
            int c2 = idx / 25;
            int w4 = idx - c2 * 25;
            const float* p0 = src + (size_t)(2 * c2) * HWP + w4 * 4;
            float4 va = *reinterpret_cast<const float4*>(p0);        // ch 2*c2
            float4 vb = *reinterpret_cast<const float4*>(p0 + HWP);  // ch 2*c2+1
            __half2 h0 = __floats2half2_rn(va.x, vb.x);
            __half2 h1 = __floats2half2_rn(va.y, vb.y);
            __half2 h2 = __floats2half2_rn(va.z, vb.z);
            __half2 h3 = __floats2half2_rn(va.w, vb.w);
            tileT[w4 * 4 + 0][c2] = *reinterpret_cast<uint*>(&h0);
            tileT[w4 * 4 + 1][c2] = *reinterpret_cast<uint*>(&h1);
            tileT[w4 * 4 + 2][c2] = *reinterpret_cast<uint*>(&h2);
            tileT[w4 * 4 + 3][c2] = *reinterpret_cast<uint*>(&h3);
        }
        __syncthreads();

        uint2* dst = reinterpret_cast<uint2*>(xT + (size_t)bh * WW * CC);
        for (int idx = threadIdx.x; idx < WW * (CC / 4); idx += 256) {
            int w = idx >> 6;           // CC/4 = 64
            int c4 = idx & 63;
            dst[idx] = make_uint2(tileT[w][2 * c4], tileT[w][2 * c4 + 1]);
        }
        return;
    }

    // ---- geometry part ----
    int p = (blockIdx.x - NT_BLOCKS) * 256 + threadIdx.x;
    if (p >= NPIX) return;
    int b = p / HWP;
    int hw = p - b * HWP;
    int h = hw / WW;
    int w = hw - h * WW;
    const float* offp = off + (size_t)b * 18 * HWP + hw;
    int bH = b * HH;
#pragma unroll
    for (int k = 0; k < 9; ++k) {
        int kh = k / 3 - 1;
        int kw = k - (k / 3) * 3 - 1;
        float dy = offp[(size_t)(2 * k) * HWP];
        float dx = offp[(size_t)(2 * k + 1) * HWP];
        float py = (float)(h + kh) + dy;
        float px = (float)(w + kw) + dx;
        float y0f = floorf(py), x0f = floorf(px);
        float wy = py - y0f, wx = px - x0f;
        int y0 = (int)y0f, x0 = (int)x0f;
        int y1 = y0 + 1, x1 = x0 + 1;
        bool vy0 = (y0 >= 0) && (y0 < HH);
        bool vy1 = (y1 >= 0) && (y1 < HH);
        bool vx0 = (x0 >= 0) && (x0 < WW);
        bool vx1 = (x1 >= 0) && (x1 < WW);
        int yc0 = min(max(y0, 0), HH - 1);
        int yc1 = min(max(y1, 0), HH - 1);
        int xc0 = min(max(x0, 0), WW - 1);
        int xc1 = min(max(x1, 0), WW - 1);
        float w00 = (1.f - wy) * (1.f - wx) * (float)(vy0 && vx0);
        float w01 = (1.f - wy) * wx * (float)(vy0 && vx1);
        float w10 = wy * (1.f - wx) * (float)(vy1 && vx0);
        float w11 = wy * wx * (float)(vy1 && vx1);
        int o00 = ((bH + yc0) * WW + xc0) * (CC * 2);
        int o01 = ((bH + yc0) * WW + xc1) * (CC * 2);
        int o10 = ((bH + yc1) * WW + xc0) * (CC * 2);
        int o11 = ((bH + yc1) * WW + xc1) * (CC * 2);
        __half2 h00 = __floats2half2_rn(w00, w00);
        __half2 h01 = __floats2half2_rn(w01, w01);
        __half2 h10 = __floats2half2_rn(w10, w10);
        __half2 h11 = __floats2half2_rn(w11, w11);
        int4* rec = geom + ((size_t)p * 9 + k) * 2;
        rec[0] = make_int4(o00, o01, o10, o11);
        rec[1] = make_int4(*reinterpret_cast<int*>(&h00), *reinterpret_cast<int*>(&h01),
                           *reinterpret_cast<int*>(&h10), *reinterpret_cast<int*>(&h11));
    }
}

// ---------------------------------------------------------------------------
// Pass 2: 4 waves per block; each WAVE owns one pixel; lane = 4 channels.
// Load-all-then-compute: all 36 corner uint2 loads issued before any math
// so the wave keeps ~36 vmem requests in flight (MLP), then packed fp16
// FMA/max. Geometry via wave-uniform s_load, weights broadcast from SGPRs.
// ---------------------------------------------------------------------------
__global__ __launch_bounds__(256) void deform2_kernel(
    const char* __restrict__ xTb, const int4* __restrict__ geom,
    const float* __restrict__ w0, const float* __restrict__ b0,
    float* __restrict__ out, int nblk) {
    // bijective XCD chunk swizzle
    int orig = blockIdx.x;
    int q = nblk / 8, r = nblk % 8;
    int xcd = orig % 8, idx = orig / 8;
    int bid = (xcd < r) ? (xcd * (q + 1) + idx)
                        : (r * (q + 1) + (xcd - r) * q + idx);

    int lane = threadIdx.x & 63;
    int wid = threadIdx.x >> 6;
    int p = __builtin_amdgcn_readfirstlane(bid * 4 + wid);  // wave-uniform pixel

    const int4* g = geom + (size_t)p * 9 * 2;
    int laneOff = lane * 8;

    // ---- stage 1: pull all geometry (s_load) ----
    int4 o_[9];
    int4 wb_[9];
#pragma unroll
    for (int k = 0; k < 9; ++k) {
        o_[k] = g[k * 2];
        wb_[k] = g[k * 2 + 1];
    }

    // ---- stage 2: issue all 36 corner loads ----
    uint2 u[9][4];
#pragma unroll
    for (int k = 0; k < 9; ++k) {
        u[k][0] = *reinterpret_cast<const uint2*>(xTb + o_[k].x + laneOff);
        u[k][1] = *reinterpret_cast<const uint2*>(xTb + o_[k].y + laneOff);
        u[k][2] = *reinterpret_cast<const uint2*>(xTb + o_[k].z + laneOff);
        u[k][3] = *reinterpret_cast<const uint2*>(xTb + o_[k].w + laneOff);
    }

    // ---- stage 3: packed fp16 bilinear + max ----
    const ushort NEG_INF_H = 0xFC00;
    uint m0 = ((uint)NEG_INF_H << 16) | NEG_INF_H;
    uint m1 = m0;

#pragma unroll
    for (int k = 0; k < 9; ++k) {
        __half2 w00 = *reinterpret_cast<__half2*>(&wb_[k].x);
        __half2 w01 = *reinterpret_cast<__half2*>(&wb_[k].y);
        __half2 w10 = *reinterpret_cast<__half2*>(&wb_[k].z);
        __half2 w11 = *reinterpret_cast<__half2*>(&wb_[k].w);

        __half2 a; uint au;
        au = u[k][0].x; a = *reinterpret_cast<__half2*>(&au);
        __half2 acc0 = __hmul2(a, w00);
        au = u[k][0].y; a = *reinterpret_cast<__half2*>(&au);
        __half2 acc1 = __hmul2(a, w00);
        au = u[k][1].x; a = *reinterpret_cast<__half2*>(&au);
        acc0 = __hfma2(a, w01, acc0);
        au = u[k][1].y; a = *reinterpret_cast<__half2*>(&au);
        acc1 = __hfma2(a, w01, acc1);
        au = u[k][2].x; a = *reinterpret_cast<__half2*>(&au);
        acc0 = __hfma2(a, w10, acc0);
        au = u[k][2].y; a = *reinterpret_cast<__half2*>(&au);
        acc1 = __hfma2(a, w10, acc1);
        au = u[k][3].x; a = *reinterpret_cast<__half2*>(&au);
        acc0 = __hfma2(a, w11, acc0);
        au = u[k][3].y; a = *reinterpret_cast<__half2*>(&au);
        acc1 = __hfma2(a, w11, acc1);

        m0 = pk_max_f16(m0, *reinterpret_cast<uint*>(&acc0));
        m1 = pk_max_f16(m1, *reinterpret_cast<uint*>(&acc1));
    }

    float2 f0 = __half22float2(*reinterpret_cast<__half2*>(&m0)); // ch 4l,4l+1
    float2 f1 = __half22float2(*reinterpret_cast<__half2*>(&m1)); // ch 4l+2,4l+3
    float4 wq = reinterpret_cast<const float4*>(w0)[lane];
    float part = f0.x * wq.x + f0.y * wq.y + f1.x * wq.z + f1.y * wq.w;
#pragma unroll
    for (int d = 32; d > 0; d >>= 1) part += __shfl_down(part, d, 64);
    if (lane == 0) {
        float z = part + b0[0];
        out[p] = 1.f / (1.f + expf(-z));
    }
}

// ---------------------------------------------------------------------------
// Fallback: one block (128 threads) per pixel, f32 path, no workspace needed.
// ---------------------------------------------------------------------------
__global__ __launch_bounds__(128) void deform_fallback_kernel(
    const float* __restrict__ x, const float* __restrict__ off,
    const float* __restrict__ w0, const float* __restrict__ b0,
    float* __restrict__ out) {
    int p = blockIdx.x;
    int b = p / HWP;
    int hw = p - b * HWP;
    int h = hw / WW;
    int w = hw - h * WW;
    int tid = threadIdx.x;

    const float* offp = off + (size_t)b * 18 * HWP + hw;
    const float* xb = x + (size_t)b * CC * HWP + (size_t)(2 * tid) * HWP;

    float m0 = -INFINITY, m1 = -INFINITY;

#pragma unroll
    for (int k = 0; k < 9; ++k) {
        int kh = k / 3 - 1;
        int kw = k - (k / 3) * 3 - 1;
        float dy = offp[(size_t)(2 * k) * HWP];
        float dx = offp[(size_t)(2 * k + 1) * HWP];
        float py = (float)(h + kh) + dy;
        float px = (float)(w + kw) + dx;
        float y0f = floorf(py), x0f = floorf(px);
        float wy = py - y0f, wx = px - x0f;
        int y0 = (int)y0f, x0 = (int)x0f;
        int y1 = y0 + 1, x1 = x0 + 1;
        bool vy0 = (y0 >= 0) && (y0 < HH);
        bool vy1 = (y1 >= 0) && (y1 < HH);
        bool vx0 = (x0 >= 0) && (x0 < WW);
        bool vx1 = (x1 >= 0) && (x1 < WW);
        int yc0 = min(max(y0, 0), HH - 1);
        int yc1 = min(max(y1, 0), HH - 1);
        int xc0 = min(max(x0, 0), WW - 1);
        int xc1 = min(max(x1, 0), WW - 1);
        float w00 = (1.f - wy) * (1.f - wx) * (float)(vy0 && vx0);
        float w01 = (1.f - wy) * wx * (float)(vy0 && vx1);
        float w10 = wy * (1.f - wx) * (float)(vy1 && vx0);
        float w11 = wy * wx * (float)(vy1 && vx1);

        int o00 = yc0 * WW + xc0, o01 = yc0 * WW + xc1;
        int o10 = yc1 * WW + xc0, o11 = yc1 * WW + xc1;
        float s0 = xb[o00] * w00 + xb[o01] * w01 + xb[o10] * w10 + xb[o11] * w11;
        float s1 = xb[o00 + HWP] * w00 + xb[o01 + HWP] * w01 +
                   xb[o10 + HWP] * w10 + xb[o11 + HWP] * w11;
        m0 = fmaxf(m0, s0);
        m1 = fmaxf(m1, s1);
    }

    float2 wv = reinterpret_cast<const float2*>(w0)[tid];
    float partial = m0 * wv.x + m1 * wv.y;
#pragma unroll
    for (int d = 32; d > 0; d >>= 1) partial += __shfl_down(partial, d, 64);

    __shared__ float red[2];
    if ((tid & 63) == 0) red[tid >> 6] = partial;
    __syncthreads();
    if (tid == 0) {
        float z = red[0] + red[1] + b0[0];
        out[p] = 1.f / (1.f + expf(-z));
    }
}

extern "C" void kernel_launch(void* const* d_in, const int* in_sizes, int n_in,
                              void* d_out, int out_size, void* d_ws, size_t ws_size,
                              hipStream_t stream) {
    const float* x   = (const float*)d_in[0];
    const float* off = (const float*)d_in[1];
    const float* w0  = (const float*)d_in[2];
    const float* b0  = (const float*)d_in[3];
    float* out = (float*)d_out;

    if (ws_size >= XT_BYTES + GEOM_BYTES) {
        ushort* xT = (ushort*)d_ws;
        int4* geom = (int4*)((char*)d_ws + XT_BYTES);
        prep_kernel<<<NT_BLOCKS + NG_BLOCKS, 256, 0, stream>>>(x, xT, off, geom);
        int nblk = NPIX / 4;  // 10000
        deform2_kernel<<<nblk, 256, 0, stream>>>((const char*)d_ws, geom, w0, b0, out, nblk);
    } else {
        deform_fallback_kernel<<<NPIX, 128, 0, stream>>>(x, off, w0, b0, out);
    }
}